// Round 5
// baseline (1236.271 us; speedup 1.0000x reference)
//
#include <hip/hip_runtime.h>

static constexpr int H = 128, W = 128, HW = H * W;
static constexpr int PW = 130;  // padded width/height for NHWC bf16 activation buffers

typedef __attribute__((ext_vector_type(8))) short short8;
typedef __attribute__((ext_vector_type(4))) float f32x4;
typedef unsigned int uint;
typedef unsigned short ushort;

__device__ __forceinline__ float silu_f(float v) { return v / (1.f + __expf(-v)); }
__device__ __forceinline__ ushort f2bf(float f) {
    uint u = __builtin_bit_cast(uint, f);
    return (ushort)((u + 0x7FFFu + ((u >> 16) & 1u)) >> 16);
}
__device__ __forceinline__ float bf2f(ushort s) {
    return __builtin_bit_cast(float, (uint)s << 16);
}

// ================= prep: stats zero, polar, wt transposes, split MFMA weight packs =================
struct PrepArgs {
    const float *w1, *w2, *w3, *wp1, *wp2;
    float *wt1, *wtp1, *polar, *stats;
    ushort *wpk2h, *wpk2l, *wpk3h, *wpk3l, *wpkph, *wpkpl;
    int nstats;
};

__global__ void prep_k(PrepArgs a) {
    int tid = blockIdx.x * 256 + threadIdx.x;
    int stride = gridDim.x * 256;
    for (int i = tid; i < a.nstats; i += stride) a.stats[i] = 0.f;
    for (int i = tid; i < HW; i += stride) {
        int yy = i >> 7, xx = i & 127;
        float X = -1.f + 2.f * xx / 127.f;
        float Y = -1.f + 2.f * yy / 127.f;
        float r = sqrtf(X * X + Y * Y);
        float inv = (r > 0.f) ? 1.f / r : 0.f;
        a.polar[i] = r;
        a.polar[HW + i] = (r > 0.f) ? X * inv : 1.f;
        a.polar[2 * HW + i] = Y * inv;
    }
    // conv1/convp1 fp32 weight transpose -> [cin*9][cout]
    for (int i = tid; i < 4 * 9 * 32; i += stride) {
        int cout = i / 36, rem = i % 36;
        a.wt1[rem * 32 + cout] = a.w1[i];
    }
    for (int i = tid; i < 4 * 9 * 16; i += stride) {
        int cout = i / 36, rem = i % 36;
        a.wtp1[rem * 16 + cout] = a.wp1[i];
    }
    // wpack2: conv2 (Cin32->Cout32), [(q*2+nt)][lane][8], k=(l>>4)*8+j=cin, n=nt*16+(l&15)
    for (int i = tid; i < 9 * 2 * 64 * 8; i += stride) {
        int j = i & 7, l = (i >> 3) & 63, t = i >> 9;
        int q = t >> 1, nt = t & 1;
        int k = (l >> 4) * 8 + j;
        int n = nt * 16 + (l & 15);
        int ky = q / 3, kx = q % 3;
        float w = a.w2[((n * 32 + k) * 3 + ky) * 3 + kx];
        ushort h = f2bf(w);
        a.wpk2h[i] = h;
        a.wpk2l[i] = f2bf(w - bf2f(h));
    }
    // wpack3: conv3 (Cin32->Cout16)
    for (int i = tid; i < 9 * 64 * 8; i += stride) {
        int j = i & 7, l = (i >> 3) & 63, q = i >> 9;
        int k = (l >> 4) * 8 + j;
        int n = l & 15;
        int ky = q / 3, kx = q % 3;
        float w = a.w3[((n * 32 + k) * 3 + ky) * 3 + kx];
        ushort h = f2bf(w);
        a.wpk3h[i] = h;
        a.wpk3l[i] = f2bf(w - bf2f(h));
    }
    // wpackp: convp2 (Cin16->Cout16), K=[tap][cin16] in chunks of 32, zero-pad tap>8
    for (int i = tid; i < 5 * 64 * 8; i += stride) {
        int j = i & 7, l = (i >> 3) & 63, q = i >> 9;
        int kg = q * 32 + (l >> 4) * 8 + j;
        int tap = kg >> 4, cin = kg & 15;
        int n = l & 15;
        float w = 0.f;
        if (tap < 9) w = a.wp2[((n * 16 + cin) * 3 + tap / 3) * 3 + tap % 3];
        ushort h = f2bf(w);
        a.wpkph[i] = h;
        a.wpkpl[i] = f2bf(w - bf2f(h));
    }
}

// zero borders of a padded [B][PW][PW][CH] bf16 buffer
__global__ void border_k(ushort* __restrict__ nb, int CH, int Bc) {
    int tid = blockIdx.x * 256 + threadIdx.x;
    int stride = gridDim.x * 256;
    int tot = Bc * 516;
    uint4 z = {0, 0, 0, 0};
    for (int i = tid; i < tot; i += stride) {
        int ib = i / 516, e = i % 516;
        int py, px;
        if (e < 130)      { py = 0;       px = e; }
        else if (e < 260) { py = 129;     px = e - 130; }
        else if (e < 388) { py = e - 259; px = 0; }
        else              { py = e - 387; px = 129; }
        ushort* p = nb + ((size_t)(ib * PW + py) * PW + px) * CH;
        for (int c = 0; c < CH; c += 8) *(uint4*)(p + c) = z;
    }
}

// ================= conv1 / convp1: fp32 direct (K=36), out = raw fp32 NHWC + stats =================
template <int COUT, int G>
__global__ __launch_bounds__(256) void conv1_k(
    const float* __restrict__ img, const float* __restrict__ polar,
    const float* __restrict__ wt, const float* __restrict__ bias,
    float* __restrict__ outraw, float* __restrict__ stats) {
    const int tid = threadIdx.x;
    const int y = blockIdx.x * 2 + (tid >> 7);
    const int x = tid & 127;
    const int b = blockIdx.y;

    float acc[COUT];
#pragma unroll
    for (int c = 0; c < COUT; c++) acc[c] = bias[c];

#pragma unroll
    for (int cin = 0; cin < 4; cin++) {
        const float* pl = (cin == 0) ? img + (size_t)b * HW : polar + (size_t)(cin - 1) * HW;
#pragma unroll
        for (int ky = 0; ky < 3; ky++) {
            int yy = y + ky - 1;
            if (yy >= 0 && yy < H) {
                const float* row = pl + yy * W;
                float v1 = row[x];
                float v0 = (x > 0) ? row[x - 1] : 0.f;
                float v2 = (x < 127) ? row[x + 1] : 0.f;
                const float* wr = wt + (cin * 9 + ky * 3) * COUT;
#pragma unroll
                for (int c = 0; c < COUT; c++) {
                    acc[c] = fmaf(wr[c], v0, acc[c]);
                    acc[c] = fmaf(wr[COUT + c], v1, acc[c]);
                    acc[c] = fmaf(wr[2 * COUT + c], v2, acc[c]);
                }
            }
        }
    }

    float4* ob = (float4*)(outraw + ((size_t)b * HW + y * W + x) * COUT);
#pragma unroll
    for (int i = 0; i < COUT / 4; i++)
        ob[i] = make_float4(acc[4 * i], acc[4 * i + 1], acc[4 * i + 2], acc[4 * i + 3]);

    constexpr int CgO = COUT / G;
    __shared__ float sred[4][G][2];
    const int lane = tid & 63, wid = tid >> 6;
#pragma unroll
    for (int g = 0; g < G; g++) {
        float s = 0.f, s2 = 0.f;
#pragma unroll
        for (int c = g * CgO; c < (g + 1) * CgO; c++) { s += acc[c]; s2 += acc[c] * acc[c]; }
#pragma unroll
        for (int off = 32; off > 0; off >>= 1) {
            s += __shfl_down(s, off);
            s2 += __shfl_down(s2, off);
        }
        if (lane == 0) { sred[wid][g][0] = s; sred[wid][g][1] = s2; }
    }
    __syncthreads();
    if (tid < G) {
        float s = 0.f, s2 = 0.f;
#pragma unroll
        for (int w = 0; w < 4; w++) { s += sred[w][tid][0]; s2 += sred[w][tid][1]; }
        atomicAdd(&stats[((size_t)b * G + tid) * 2], s);
        atomicAdd(&stats[((size_t)b * G + tid) * 2 + 1], s2);
    }
}

// ========= normpack: raw fp32 NHWC + stats -> GN+SiLU -> padded NHWC bf16 hi/lo (2C ch) =========
template <int C, int G>
__global__ __launch_bounds__(256) void normpack_k(
    const float* __restrict__ raw, const float* __restrict__ stats,
    const float* __restrict__ gamma, const float* __restrict__ beta,
    ushort* __restrict__ nb) {
    constexpr int C4 = C / 4;
    const int b = blockIdx.y;
    __shared__ float la[C], lc[C];
    int tid = threadIdx.x;
    if (tid < C) {
        constexpr float inv = 1.f / ((C / G) * (float)HW);
        int g = tid / (C / G);
        float s = stats[((size_t)b * G + g) * 2];
        float s2 = stats[((size_t)b * G + g) * 2 + 1];
        float m = s * inv;
        float rs = rsqrtf(s2 * inv - m * m + 1e-5f);
        float aa = gamma[tid] * rs;
        la[tid] = aa;
        lc[tid] = beta[tid] - m * aa;
    }
    __syncthreads();
    int idx = blockIdx.x * 256 + tid;
    int px = idx / C4, cg = idx % C4;
    float4 v = *(const float4*)(raw + ((size_t)b * HW + px) * C + cg * 4);
    float f0 = silu_f(fmaf(v.x, la[cg * 4 + 0], lc[cg * 4 + 0]));
    float f1 = silu_f(fmaf(v.y, la[cg * 4 + 1], lc[cg * 4 + 1]));
    float f2 = silu_f(fmaf(v.z, la[cg * 4 + 2], lc[cg * 4 + 2]));
    float f3 = silu_f(fmaf(v.w, la[cg * 4 + 3], lc[cg * 4 + 3]));
    ushort h0 = f2bf(f0), h1 = f2bf(f1), h2 = f2bf(f2), h3_ = f2bf(f3);
    ushort l0 = f2bf(f0 - bf2f(h0)), l1 = f2bf(f1 - bf2f(h1));
    ushort l2 = f2bf(f2 - bf2f(h2)), l3 = f2bf(f3 - bf2f(h3_));
    size_t ob = ((size_t)(b * PW + (px >> 7) + 1) * PW + (px & 127) + 1) * (2 * C);
    *(ushort4*)(nb + ob + cg * 4)     = make_ushort4(h0, h1, h2, h3_);
    *(ushort4*)(nb + ob + C + cg * 4) = make_ushort4(l0, l1, l2, l3);
}

// ================= split MFMA conv 3x3, Cin=32 (conv2: COUT=32, conv3: COUT=16) =================
// nb: [b][py][px][64] = hi(0..31) lo(32..63). 3 terms: Whi*xhi + Whi*xlo + Wlo*xhi.
template <int COUT, int G>
__global__ __launch_bounds__(256) void conv_mfma_c32(
    const ushort* __restrict__ nb, const float* __restrict__ bias,
    const short8* __restrict__ wph, const short8* __restrict__ wpl,
    float* __restrict__ outraw, float* __restrict__ stats) {
    constexpr int NT = COUT / 16;
    const int tid = threadIdx.x;
    const int wid = tid >> 6, l = tid & 63;
    const int lm = l & 15, lk = l >> 4;
    const int y = blockIdx.x, b = blockIdx.y;

    const ushort* pb = nb + ((size_t)(b * PW + y) * PW) * 64 + lk * 8;

    f32x4 acc[2][NT];
#pragma unroll
    for (int f = 0; f < 2; f++)
#pragma unroll
        for (int nt = 0; nt < NT; nt++) acc[f][nt] = (f32x4){0.f, 0.f, 0.f, 0.f};

#pragma unroll
    for (int q = 0; q < 9; q++) {
        const int ky = q / 3, kx = q % 3;
        short8 wh[NT], wl[NT];
#pragma unroll
        for (int nt = 0; nt < NT; nt++) {
            wh[nt] = wph[(q * NT + nt) * 64 + l];
            wl[nt] = wpl[(q * NT + nt) * 64 + l];
        }
#pragma unroll
        for (int f = 0; f < 2; f++) {
            const int xb = wid * 16 + f * 64 + lm + kx;
            const ushort* ap = pb + ((size_t)ky * PW + xb) * 64;
            short8 ah = *(const short8*)ap;
            short8 al = *(const short8*)(ap + 32);
#pragma unroll
            for (int nt = 0; nt < NT; nt++) {
                acc[f][nt] = __builtin_amdgcn_mfma_f32_16x16x32_bf16(ah, wh[nt], acc[f][nt], 0, 0, 0);
                acc[f][nt] = __builtin_amdgcn_mfma_f32_16x16x32_bf16(al, wh[nt], acc[f][nt], 0, 0, 0);
                acc[f][nt] = __builtin_amdgcn_mfma_f32_16x16x32_bf16(ah, wl[nt], acc[f][nt], 0, 0, 0);
            }
        }
    }

    float bv[NT], sa[NT], sa2[NT];
#pragma unroll
    for (int nt = 0; nt < NT; nt++) { bv[nt] = bias[nt * 16 + lm]; sa[nt] = 0.f; sa2[nt] = 0.f; }

#pragma unroll
    for (int f = 0; f < 2; f++)
#pragma unroll
        for (int r = 0; r < 4; r++) {
            int x = wid * 16 + f * 64 + lk * 4 + r;
            size_t pxo = ((size_t)b * HW + y * W + x) * COUT;
#pragma unroll
            for (int nt = 0; nt < NT; nt++) {
                float v = acc[f][nt][r] + bv[nt];
                outraw[pxo + nt * 16 + lm] = v;
                sa[nt] += v;
                sa2[nt] += v * v;
            }
        }

    constexpr int CgO = COUT / G;
#pragma unroll
    for (int nt = 0; nt < NT; nt++) {
        float s = sa[nt], s2 = sa2[nt];
        s += __shfl_xor(s, 16); s2 += __shfl_xor(s2, 16);
        s += __shfl_xor(s, 32); s2 += __shfl_xor(s2, 32);
#pragma unroll
        for (int m = 1; m < CgO; m <<= 1) { s += __shfl_xor(s, m); s2 += __shfl_xor(s2, m); }
        if (l < 16 && (lm & (CgO - 1)) == 0) {
            int g = (nt * 16 + lm) / CgO;
            atomicAdd(&stats[((size_t)b * G + g) * 2], s);
            atomicAdd(&stats[((size_t)b * G + g) * 2 + 1], s2);
        }
    }
}

// ================= split MFMA conv 3x3, Cin=16 -> Cout=16 (convp2), K padded 144->160 =================
// nb: [b][py][px][32] = hi(0..15) lo(16..31)
__global__ __launch_bounds__(256) void conv_mfma_c16(
    const ushort* __restrict__ nb, const float* __restrict__ bias,
    const short8* __restrict__ wph, const short8* __restrict__ wpl,
    float* __restrict__ outraw, float* __restrict__ stats) {
    const int tid = threadIdx.x;
    const int wid = tid >> 6, l = tid & 63;
    const int lm = l & 15, lk = l >> 4;
    const int y = blockIdx.x, b = blockIdx.y;
    const int hi2 = lk >> 1;

    const ushort* pb = nb + ((size_t)(b * PW + y) * PW) * 32 + (lk & 1) * 8;

    int offq[5];
#pragma unroll
    for (int q = 0; q < 5; q++) {
        int tap = 2 * q + hi2;
        if (tap > 8) tap = 8;
        int ky = tap / 3, kx = tap - 3 * ky;
        offq[q] = (ky * PW + kx) * 32;
    }

    f32x4 acc[2];
    acc[0] = (f32x4){0.f, 0.f, 0.f, 0.f};
    acc[1] = (f32x4){0.f, 0.f, 0.f, 0.f};

#pragma unroll
    for (int q = 0; q < 5; q++) {
        short8 wh = wph[q * 64 + l];
        short8 wl = wpl[q * 64 + l];
#pragma unroll
        for (int f = 0; f < 2; f++) {
            const int x0 = wid * 16 + f * 64;
            const ushort* ap = pb + offq[q] + (size_t)(x0 + lm) * 32;
            short8 ah = *(const short8*)ap;
            short8 al = *(const short8*)(ap + 16);
            acc[f] = __builtin_amdgcn_mfma_f32_16x16x32_bf16(ah, wh, acc[f], 0, 0, 0);
            acc[f] = __builtin_amdgcn_mfma_f32_16x16x32_bf16(al, wh, acc[f], 0, 0, 0);
            acc[f] = __builtin_amdgcn_mfma_f32_16x16x32_bf16(ah, wl, acc[f], 0, 0, 0);
        }
    }

    float bv = bias[lm];
    float sa = 0.f, sa2 = 0.f;
#pragma unroll
    for (int f = 0; f < 2; f++)
#pragma unroll
        for (int r = 0; r < 4; r++) {
            int x = wid * 16 + f * 64 + lk * 4 + r;
            float v = acc[f][r] + bv;
            outraw[((size_t)b * HW + y * W + x) * 16 + lm] = v;
            sa += v;
            sa2 += v * v;
        }
    float s = sa, s2 = sa2;
    s += __shfl_xor(s, 16); s2 += __shfl_xor(s2, 16);
    s += __shfl_xor(s, 32); s2 += __shfl_xor(s2, 32);
    s += __shfl_xor(s, 1);  s2 += __shfl_xor(s2, 1);
    s += __shfl_xor(s, 2);  s2 += __shfl_xor(s2, 2);
    if (l < 16 && (lm & 3) == 0) {
        int g = lm >> 2;
        atomicAdd(&stats[((size_t)b * 4 + g) * 2], s);
        atomicAdd(&stats[((size_t)b * 4 + g) * 2 + 1], s2);
    }
}

// ================= psik: GN+SiLU on fp32 NHWC h3/p2 + 1x1 convs -> k, psi =================
__global__ void psik_k(const float* __restrict__ h3, const float* __restrict__ p2,
                       const float* __restrict__ kg3, const float* __restrict__ kbeta3,
                       const float* __restrict__ st3,
                       const float* __restrict__ pg2, const float* __restrict__ pbeta2,
                       const float* __restrict__ stp2,
                       const float* __restrict__ kw4, const float* __restrict__ kb4,
                       const float* __restrict__ pw3, const float* __restrict__ pb3,
                       float* __restrict__ outk, float* __restrict__ outpsi, int Bc) {
    int n = blockIdx.x * 256 + threadIdx.x;
    if (n >= Bc * HW) return;
    int b = n >> 14;
    int rem = n & (HW - 1);
    int i = rem >> 7;
    int j = rem & 127;

    constexpr float inv = 1.f / (float)(4 * HW);
    float a3[4], c3[4], ap[4], cp[4];
#pragma unroll
    for (int g = 0; g < 4; g++) {
        float s = st3[((size_t)b * 4 + g) * 2];
        float s2 = st3[((size_t)b * 4 + g) * 2 + 1];
        float m = s * inv;
        a3[g] = rsqrtf(s2 * inv - m * m + 1e-5f);
        c3[g] = m;
        s = stp2[((size_t)b * 4 + g) * 2];
        s2 = stp2[((size_t)b * 4 + g) * 2 + 1];
        m = s * inv;
        ap[g] = rsqrtf(s2 * inv - m * m + 1e-5f);
        cp[g] = m;
    }

    float hv[16], pv[16];
    const float4* hp = (const float4*)(h3 + ((size_t)b * HW + rem) * 16);
    const float4* pp = (const float4*)(p2 + ((size_t)b * HW + rem) * 16);
#pragma unroll
    for (int t = 0; t < 4; t++) {
        float4 u = hp[t];
        hv[4 * t] = u.x; hv[4 * t + 1] = u.y; hv[4 * t + 2] = u.z; hv[4 * t + 3] = u.w;
        float4 w = pp[t];
        pv[4 * t] = w.x; pv[4 * t + 1] = w.y; pv[4 * t + 2] = w.z; pv[4 * t + 3] = w.w;
    }

    float dk = kb4[0], dp = pb3[0];
#pragma unroll
    for (int c = 0; c < 16; c++) {
        int g = c >> 2;
        float a = kg3[c] * a3[g];
        float t = fmaf(hv[c] - c3[g], a, kbeta3[c]);
        dk = fmaf(kw4[c], silu_f(t), dk);
        a = pg2[c] * ap[g];
        t = fmaf(pv[c] - cp[g], a, pbeta2[c]);
        dp = fmaf(pw3[c], silu_f(t), dp);
    }
    float k = 0.5f * (1.f + 0.3f * tanhf(dk));
    float psr = 0.05f * tanhf(dp);
    float X = -1.f + 2.f * j / 127.f;
    float Y = -1.f + 2.f * i / 127.f;
    float r = sqrtf(X * X + Y * Y);
    outk[n] = k;
    outpsi[n] = fmaf(k, r, psr);
}

// ================= blur + final =================
static __device__ __constant__ float GW0 = 0.40261994689423467f;
static __device__ __constant__ float GW1 = 0.24420134200323348f;
static __device__ __constant__ float GW2 = 0.05448868454964433f;

__global__ void blur_h_k(const float* __restrict__ in, float* __restrict__ out, int B) {
    int n = blockIdx.x * 256 + threadIdx.x;
    if (n >= B * HW) return;
    int j = n & 127;
    const float* row = in + (n - j);
    int jm2 = j - 2; jm2 = jm2 < 0 ? -jm2 : jm2;
    int jm1 = j - 1; jm1 = jm1 < 0 ? -jm1 : jm1;
    int jp1 = j + 1; jp1 = jp1 > 127 ? 254 - jp1 : jp1;
    int jp2 = j + 2; jp2 = jp2 > 127 ? 254 - jp2 : jp2;
    out[n] = GW2 * (row[jm2] + row[jp2]) + GW1 * (row[jm1] + row[jp1]) + GW0 * row[j];
}

__global__ void blur_v_k(const float* __restrict__ in, float* __restrict__ out, int B) {
    int n = blockIdx.x * 256 + threadIdx.x;
    if (n >= B * HW) return;
    int rem = n & (HW - 1);
    int i = rem >> 7;
    int j = rem & 127;
    const float* pl = in + (n - rem) + j;
    int im2 = i - 2; im2 = im2 < 0 ? -im2 : im2;
    int im1 = i - 1; im1 = im1 < 0 ? -im1 : im1;
    int ip1 = i + 1; ip1 = ip1 > 127 ? 254 - ip1 : ip1;
    int ip2 = i + 2; ip2 = ip2 > 127 ? 254 - ip2 : ip2;
    out[n] = GW2 * (pl[im2 * W] + pl[ip2 * W]) + GW1 * (pl[im1 * W] + pl[ip1 * W]) + GW0 * pl[i * W];
}

__global__ void final_k(const float* __restrict__ psis, const float* __restrict__ img,
                        float* __restrict__ osrc, float* __restrict__ oax,
                        float* __restrict__ oay, int B) {
    int n = blockIdx.x * 256 + threadIdx.x;
    if (n >= B * HW) return;
    int rem = n & (HW - 1);
    int i = rem >> 7;
    int j = rem & 127;
    const float* pl = psis + (n - rem);

    float gx;
    if (j == 0)        gx = pl[i * W + 1] - pl[i * W];
    else if (j == 127) gx = pl[i * W + 127] - pl[i * W + 126];
    else               gx = (pl[i * W + j + 1] - pl[i * W + j - 1]) * 0.5f;
    gx *= 63.5f;

    float gy;
    if (i == 0)        gy = pl[W + j] - pl[j];
    else if (i == 127) gy = pl[127 * W + j] - pl[126 * W + j];
    else               gy = (pl[(i + 1) * W + j] - pl[(i - 1) * W + j]) * 0.5f;
    gy *= 63.5f;

    float ax = 0.5f * tanhf(gx * 2.f);
    float ay = 0.5f * tanhf(gy * 2.f);

    float X = -1.f + 2.f * j / 127.f;
    float Y = -1.f + 2.f * i / 127.f;
    float bx = fminf(fmaxf(X - ax, -1.f), 1.f);
    float by = fminf(fmaxf(Y - ay, -1.f), 1.f);
    float px = (bx + 1.f) * 0.5f * 127.f;
    float py = (by + 1.f) * 0.5f * 127.f;
    float x0f = floorf(px), y0f = floorf(py);
    float wx = px - x0f, wy = py - y0f;
    int x0i = min(max((int)x0f, 0), 127);
    int x1i = min(x0i + 1, 127);
    int y0i = min(max((int)y0f, 0), 127);
    int y1i = min(y0i + 1, 127);

    const float* im = img + (size_t)(n >> 14) * HW;
    float v00 = im[y0i * W + x0i], v01 = im[y0i * W + x1i];
    float v10 = im[y1i * W + x0i], v11 = im[y1i * W + x1i];
    float wrp = v00 * (1.f - wx) * (1.f - wy) + v01 * wx * (1.f - wy) +
                v10 * (1.f - wx) * wy + v11 * wx * wy;

    osrc[n] = 0.9f * wrp + 0.1f * im[rem];
    oax[n] = ax;
    oay[n] = ay;
}

// ================= launch =================
extern "C" void kernel_launch(void* const* d_in, const int* in_sizes, int n_in,
                              void* d_out, int out_size, void* d_ws, size_t ws_size,
                              hipStream_t stream) {
    const float* img = (const float*)d_in[0];
    const int B = in_sizes[0] / HW;  // 64
    const int npix = B * HW;

    char* base = (char*)d_ws;
    size_t off = 0;
    auto alloc = [&](size_t bytes) {
        char* p = base + off;
        off = (off + bytes + 255) & ~(size_t)255;
        return p;
    };

    float* tmp   = (float*)alloc((size_t)npix * 4);
    float* psis  = (float*)alloc((size_t)npix * 4);
    float* polar = (float*)alloc(3 * HW * 4);
    float* wt1   = (float*)alloc(4 * 9 * 32 * 4);
    float* wtp1  = (float*)alloc(4 * 9 * 16 * 4);
    ushort* wpk2h = (ushort*)alloc(9 * 2 * 64 * 8 * 2);
    ushort* wpk2l = (ushort*)alloc(9 * 2 * 64 * 8 * 2);
    ushort* wpk3h = (ushort*)alloc(9 * 64 * 8 * 2);
    ushort* wpk3l = (ushort*)alloc(9 * 64 * 8 * 2);
    ushort* wpkph = (ushort*)alloc(5 * 64 * 8 * 2);
    ushort* wpkpl = (ushort*)alloc(5 * 64 * 8 * 2);
    int nstats = B * 56;
    float* stats = (float*)alloc((size_t)nstats * 4);
    float* st1  = stats;                 // B*8*2
    float* st2  = st1 + (size_t)B * 16;  // B*8*2
    float* st3  = st2 + (size_t)B * 16;  // B*4*2
    float* stp1 = st3 + (size_t)B * 8;   // B*4*2
    float* stp2 = stp1 + (size_t)B * 8;  // B*4*2
    size_t head = off;

    // chunk size: R = BC*HW*32 fp32, N1 = BC*PW*PW*64 bf16
    int BC = B;
    while (BC > 1) {
        size_t need = head + (size_t)BC * HW * 32 * 4 + 256 + (size_t)BC * PW * PW * 64 * 2;
        if (need <= ws_size) break;
        BC >>= 1;
    }
    float*  R  = (float*)alloc((size_t)BC * HW * 32 * 4);
    ushort* N1 = (ushort*)alloc((size_t)BC * PW * PW * 64 * 2);
    float* h3R  = R;                          // [BC][HW][16] fp32
    float* p2R  = R + (size_t)BC * HW * 16;   // convp1 raw, then p2

    float* outsrc = (float*)d_out;
    float* outk   = outsrc + (size_t)npix;
    float* outpsi = outk + (size_t)npix;
    float* outax  = outpsi + (size_t)npix;
    float* outay  = outax + (size_t)npix;

    PrepArgs pa;
    pa.w1 = (const float*)d_in[1]; pa.w2 = (const float*)d_in[5];
    pa.w3 = (const float*)d_in[9]; pa.wp1 = (const float*)d_in[15];
    pa.wp2 = (const float*)d_in[19];
    pa.wt1 = wt1; pa.wtp1 = wtp1; pa.polar = polar; pa.stats = stats;
    pa.wpk2h = wpk2h; pa.wpk2l = wpk2l; pa.wpk3h = wpk3h; pa.wpk3l = wpk3l;
    pa.wpkph = wpkph; pa.wpkpl = wpkpl; pa.nstats = nstats;
    prep_k<<<128, 256, 0, stream>>>(pa);

    for (int b0 = 0; b0 < B; b0 += BC) {
        const float* imgc = img + (size_t)b0 * HW;
        dim3 cg1(H / 2, BC), cgm(H, BC);
        int bgrid = (BC * 516 + 255) / 256;

        border_k<<<bgrid, 256, 0, stream>>>(N1, 64, BC);

        // k-tower
        conv1_k<32, 8><<<cg1, 256, 0, stream>>>(imgc, polar, wt1, (const float*)d_in[2],
                                                R, st1 + (size_t)b0 * 16);
        normpack_k<32, 8><<<dim3(512, BC), 256, 0, stream>>>(R, st1 + (size_t)b0 * 16,
            (const float*)d_in[3], (const float*)d_in[4], N1);
        conv_mfma_c32<32, 8><<<cgm, 256, 0, stream>>>(N1, (const float*)d_in[6],
            (const short8*)wpk2h, (const short8*)wpk2l, R, st2 + (size_t)b0 * 16);
        normpack_k<32, 8><<<dim3(512, BC), 256, 0, stream>>>(R, st2 + (size_t)b0 * 16,
            (const float*)d_in[7], (const float*)d_in[8], N1);
        conv_mfma_c32<16, 4><<<cgm, 256, 0, stream>>>(N1, (const float*)d_in[10],
            (const short8*)wpk3h, (const short8*)wpk3l, h3R, st3 + (size_t)b0 * 8);

        // p-tower (reuses upper half of R and N1-as-32ch)
        conv1_k<16, 4><<<cg1, 256, 0, stream>>>(imgc, polar, wtp1, (const float*)d_in[16],
                                                p2R, stp1 + (size_t)b0 * 8);
        border_k<<<bgrid, 256, 0, stream>>>(N1, 32, BC);
        normpack_k<16, 4><<<dim3(256, BC), 256, 0, stream>>>(p2R, stp1 + (size_t)b0 * 8,
            (const float*)d_in[17], (const float*)d_in[18], N1);
        conv_mfma_c16<<<cgm, 256, 0, stream>>>(N1, (const float*)d_in[20],
            (const short8*)wpkph, (const short8*)wpkpl, p2R, stp2 + (size_t)b0 * 8);

        int pgrid = (BC * HW + 255) / 256;
        psik_k<<<pgrid, 256, 0, stream>>>(h3R, p2R,
            (const float*)d_in[11], (const float*)d_in[12], st3 + (size_t)b0 * 8,
            (const float*)d_in[21], (const float*)d_in[22], stp2 + (size_t)b0 * 8,
            (const float*)d_in[13], (const float*)d_in[14],
            (const float*)d_in[23], (const float*)d_in[24],
            outk + (size_t)b0 * HW, outpsi + (size_t)b0 * HW, BC);
    }

    int pgrid = (npix + 255) / 256;
    blur_h_k<<<pgrid, 256, 0, stream>>>(outpsi, tmp, B);
    blur_v_k<<<pgrid, 256, 0, stream>>>(tmp, psis, B);
    final_k<<<pgrid, 256, 0, stream>>>(psis, img, outsrc, outax, outay, B);
}

// Round 6
// 1021.855 us; speedup vs baseline: 1.2098x; 1.2098x over previous
//
#include <hip/hip_runtime.h>

static constexpr int H = 128, W = 128, HW = H * W;

typedef __attribute__((ext_vector_type(8))) short short8;
typedef __attribute__((ext_vector_type(4))) float f32x4;
typedef unsigned int uint;
typedef unsigned short ushort;

__device__ __forceinline__ float silu_f(float v) { return v / (1.f + __expf(-v)); }
__device__ __forceinline__ ushort f2bf(float f) {
    uint u = __builtin_bit_cast(uint, f);
    return (ushort)((u + 0x7FFFu + ((u >> 16) & 1u)) >> 16);
}
__device__ __forceinline__ float bf2f(ushort s) {
    return __builtin_bit_cast(float, (uint)s << 16);
}

// ================= prep: stats zero, polar, wt transposes, split MFMA weight packs =================
struct PrepArgs {
    const float *w1, *w2, *w3, *wp1, *wp2;
    float *wt1, *wtp1, *polar, *stats;
    ushort *wpk2h, *wpk2l, *wpk3h, *wpk3l, *wpkph, *wpkpl;
    int nstats;
};

__global__ void prep_k(PrepArgs a) {
    int tid = blockIdx.x * 256 + threadIdx.x;
    int stride = gridDim.x * 256;
    for (int i = tid; i < a.nstats; i += stride) a.stats[i] = 0.f;
    for (int i = tid; i < HW; i += stride) {
        int yy = i >> 7, xx = i & 127;
        float X = -1.f + 2.f * xx / 127.f;
        float Y = -1.f + 2.f * yy / 127.f;
        float r = sqrtf(X * X + Y * Y);
        float inv = (r > 0.f) ? 1.f / r : 0.f;
        a.polar[i] = r;
        a.polar[HW + i] = (r > 0.f) ? X * inv : 1.f;
        a.polar[2 * HW + i] = Y * inv;
    }
    // conv1/convp1 fp32 weight transpose -> [cin*9][cout]
    for (int i = tid; i < 4 * 9 * 32; i += stride) {
        int cout = i / 36, rem = i % 36;
        a.wt1[rem * 32 + cout] = a.w1[i];
    }
    for (int i = tid; i < 4 * 9 * 16; i += stride) {
        int cout = i / 36, rem = i % 36;
        a.wtp1[rem * 16 + cout] = a.wp1[i];
    }
    // wpack2: conv2 (Cin32->Cout32), [(q*2+nt)][lane][8], k=(l>>4)*8+j=cin, n=nt*16+(l&15)
    for (int i = tid; i < 9 * 2 * 64 * 8; i += stride) {
        int j = i & 7, l = (i >> 3) & 63, t = i >> 9;
        int q = t >> 1, nt = t & 1;
        int k = (l >> 4) * 8 + j;
        int n = nt * 16 + (l & 15);
        int ky = q / 3, kx = q % 3;
        float w = a.w2[((n * 32 + k) * 3 + ky) * 3 + kx];
        ushort h = f2bf(w);
        a.wpk2h[i] = h;
        a.wpk2l[i] = f2bf(w - bf2f(h));
    }
    // wpack3: conv3 (Cin32->Cout16), [q][lane][8]
    for (int i = tid; i < 9 * 64 * 8; i += stride) {
        int j = i & 7, l = (i >> 3) & 63, q = i >> 9;
        int k = (l >> 4) * 8 + j;
        int n = l & 15;
        int ky = q / 3, kx = q % 3;
        float w = a.w3[((n * 32 + k) * 3 + ky) * 3 + kx];
        ushort h = f2bf(w);
        a.wpk3h[i] = h;
        a.wpk3l[i] = f2bf(w - bf2f(h));
    }
    // wpackp: convp2 (Cin16->Cout16), per-tap duplicated halves:
    // B1 = [Whi|Whi], B2 = [Wlo|Wlo] over k=32, cin = k&15
    for (int i = tid; i < 9 * 64 * 8; i += stride) {
        int j = i & 7, l = (i >> 3) & 63, q = i >> 9;
        int k = (l >> 4) * 8 + j;
        int cin = k & 15;
        int n = l & 15;
        float w = a.wp2[((n * 16 + cin) * 3 + q / 3) * 3 + q % 3];
        ushort h = f2bf(w);
        a.wpkph[i] = h;
        a.wpkpl[i] = f2bf(w - bf2f(h));
    }
}

// ================= conv1 / convp1: fp32 direct (K=36), out = raw fp32 NHWC + stats =================
template <int COUT, int G>
__global__ __launch_bounds__(256) void conv1_k(
    const float* __restrict__ img, const float* __restrict__ polar,
    const float* __restrict__ wt, const float* __restrict__ bias,
    float* __restrict__ outraw, float* __restrict__ stats) {
    const int tid = threadIdx.x;
    const int y = blockIdx.x * 2 + (tid >> 7);
    const int x = tid & 127;
    const int b = blockIdx.y;

    float acc[COUT];
#pragma unroll
    for (int c = 0; c < COUT; c++) acc[c] = bias[c];

#pragma unroll
    for (int cin = 0; cin < 4; cin++) {
        const float* pl = (cin == 0) ? img + (size_t)b * HW : polar + (size_t)(cin - 1) * HW;
#pragma unroll
        for (int ky = 0; ky < 3; ky++) {
            int yy = y + ky - 1;
            if (yy >= 0 && yy < H) {
                const float* row = pl + yy * W;
                float v1 = row[x];
                float v0 = (x > 0) ? row[x - 1] : 0.f;
                float v2 = (x < 127) ? row[x + 1] : 0.f;
                const float* wr = wt + (cin * 9 + ky * 3) * COUT;
#pragma unroll
                for (int c = 0; c < COUT; c++) {
                    acc[c] = fmaf(wr[c], v0, acc[c]);
                    acc[c] = fmaf(wr[COUT + c], v1, acc[c]);
                    acc[c] = fmaf(wr[2 * COUT + c], v2, acc[c]);
                }
            }
        }
    }

    float4* ob = (float4*)(outraw + ((size_t)b * HW + y * W + x) * COUT);
#pragma unroll
    for (int i = 0; i < COUT / 4; i++)
        ob[i] = make_float4(acc[4 * i], acc[4 * i + 1], acc[4 * i + 2], acc[4 * i + 3]);

    constexpr int CgO = COUT / G;
    __shared__ float sred[4][G][2];
    const int lane = tid & 63, wid = tid >> 6;
#pragma unroll
    for (int g = 0; g < G; g++) {
        float s = 0.f, s2 = 0.f;
#pragma unroll
        for (int c = g * CgO; c < (g + 1) * CgO; c++) { s += acc[c]; s2 += acc[c] * acc[c]; }
#pragma unroll
        for (int off = 32; off > 0; off >>= 1) {
            s += __shfl_down(s, off);
            s2 += __shfl_down(s2, off);
        }
        if (lane == 0) { sred[wid][g][0] = s; sred[wid][g][1] = s2; }
    }
    __syncthreads();
    if (tid < G) {
        float s = 0.f, s2 = 0.f;
#pragma unroll
        for (int w = 0; w < 4; w++) { s += sred[w][tid][0]; s2 += sred[w][tid][1]; }
        atomicAdd(&stats[((size_t)b * G + tid) * 2], s);
        atomicAdd(&stats[((size_t)b * G + tid) * 2 + 1], s2);
    }
}

// ======== fused MFMA conv 3x3: raw fp32 in -> GN+SiLU+hi/lo split in LDS -> MFMA -> raw fp32 out + stats ========
// LDS tile: 3 rows x 128 px x [hi CIN | lo CIN] bf16, XOR-swizzled:
//   byte = ((r*128+px)*LDSC + slot*8)*2 ^ ((px & SWZM)<<4), slot = ch-chunk (8 ch)
template <int CIN, int COUT, int Gin, int Gout>
__global__ __launch_bounds__(256) void conv_mfma2(
    const float* __restrict__ raw_in, const float* __restrict__ stats_in,
    const float* __restrict__ gamma, const float* __restrict__ beta,
    const float* __restrict__ bias,
    const short8* __restrict__ wph, const short8* __restrict__ wpl,
    float* __restrict__ outraw, float* __restrict__ stats_out) {
    constexpr int LDSC = 2 * CIN;           // ushorts per px-row (hi+lo)
    constexpr int SWZM = LDSC / 8 - 1;      // 7 for CIN32, 3 for CIN16
    constexpr int NT = COUT / 16;
    constexpr int NCH8 = CIN / 8;           // hi chunks per px

    __shared__ ushort tile[3 * 128 * LDSC];
    __shared__ float la[CIN], lc[CIN];
    __shared__ float sred[4][Gout][2];

    const int tid = threadIdx.x;
    const int wid = tid >> 6, l = tid & 63;
    const int lm = l & 15, lk = l >> 4;
    const int y = blockIdx.x, b = blockIdx.y;

    // GN coefficients
    if (tid < CIN) {
        constexpr float inv = 1.f / ((CIN / Gin) * (float)HW);
        int g = tid / (CIN / Gin);
        float s = stats_in[((size_t)b * Gin + g) * 2];
        float s2 = stats_in[((size_t)b * Gin + g) * 2 + 1];
        float m = s * inv;
        float rs = rsqrtf(s2 * inv - m * m + 1e-5f);
        float aa = gamma[tid] * rs;
        la[tid] = aa;
        lc[tid] = beta[tid] - m * aa;
    }
    __syncthreads();

    // ---- stage: 3 rows, normalize+silu once, split hi/lo, swizzled LDS write ----
    constexpr int PERROW = 128 * NCH8;           // 8-ch chunks per row
    constexpr int ITERS = 3 * PERROW / 256;
    char* tbw = (char*)tile;
#pragma unroll
    for (int it = 0; it < ITERS; it++) {
        int c = tid + it * 256;
        int r = c / PERROW;
        int rem = c - r * PERROW;
        int px = rem / NCH8;
        int ch8 = rem - px * NCH8;
        int yy = y - 1 + r;
        short8 hi8, lo8;
        if (yy >= 0 && yy < H) {
            const float4* gp = (const float4*)(raw_in + (((size_t)b * HW + yy * W + px) * CIN + ch8 * 8));
            float4 v0 = gp[0], v1 = gp[1];
            float vv[8] = {v0.x, v0.y, v0.z, v0.w, v1.x, v1.y, v1.z, v1.w};
#pragma unroll
            for (int e = 0; e < 8; e++) {
                int ch = ch8 * 8 + e;
                float f = silu_f(fmaf(vv[e], la[ch], lc[ch]));
                ushort h = f2bf(f);
                hi8[e] = (short)h;
                lo8[e] = (short)f2bf(f - bf2f(h));
            }
        } else {
#pragma unroll
            for (int e = 0; e < 8; e++) { hi8[e] = 0; lo8[e] = 0; }
        }
        int base = ((r * 128 + px) * LDSC) * 2;
        int swz = (px & SWZM) << 4;
        *(short8*)(tbw + ((base + ch8 * 16) ^ swz)) = hi8;
        *(short8*)(tbw + ((base + (ch8 + NCH8) * 16) ^ swz)) = lo8;
    }
    __syncthreads();

    // ---- MFMA main loop ----
    const short8 Z8 = {0, 0, 0, 0, 0, 0, 0, 0};
    const char* tb = (const char*)tile;

    f32x4 acc[2][NT];
#pragma unroll
    for (int f = 0; f < 2; f++)
#pragma unroll
        for (int nt = 0; nt < NT; nt++) acc[f][nt] = (f32x4){0.f, 0.f, 0.f, 0.f};

#pragma unroll
    for (int q = 0; q < 9; q++) {
        const int ky = q / 3, kx = q % 3;
        short8 wh[NT], wl[NT];
#pragma unroll
        for (int nt = 0; nt < NT; nt++) {
            wh[nt] = wph[(q * NT + nt) * 64 + l];
            wl[nt] = wpl[(q * NT + nt) * 64 + l];
        }
#pragma unroll
        for (int f = 0; f < 2; f++) {
            int xb = wid * 16 + f * 64 + lm + kx - 1;
            bool valid = (xb >= 0) && (xb < 128);
            int xbc = min(max(xb, 0), 127);
            int rowbase = ((ky * 128 + xbc) * LDSC) * 2;
            int swz = (xbc & SWZM) << 4;
            if constexpr (CIN == 32) {
                short8 ah = *(const short8*)(tb + ((rowbase + lk * 16) ^ swz));
                short8 al = *(const short8*)(tb + ((rowbase + (lk + 4) * 16) ^ swz));
                if (!valid) { ah = Z8; al = Z8; }
#pragma unroll
                for (int nt = 0; nt < NT; nt++) {
                    acc[f][nt] = __builtin_amdgcn_mfma_f32_16x16x32_bf16(ah, wh[nt], acc[f][nt], 0, 0, 0);
                    acc[f][nt] = __builtin_amdgcn_mfma_f32_16x16x32_bf16(al, wh[nt], acc[f][nt], 0, 0, 0);
                    acc[f][nt] = __builtin_amdgcn_mfma_f32_16x16x32_bf16(ah, wl[nt], acc[f][nt], 0, 0, 0);
                }
            } else {
                // CIN16: A = [xhi|xlo] over k=32; B1=[Whi|Whi], B2=[Wlo|Wlo]
                short8 a = *(const short8*)(tb + ((rowbase + lk * 16) ^ swz));
                if (!valid) a = Z8;
                acc[f][0] = __builtin_amdgcn_mfma_f32_16x16x32_bf16(a, wh[0], acc[f][0], 0, 0, 0);
                acc[f][0] = __builtin_amdgcn_mfma_f32_16x16x32_bf16(a, wl[0], acc[f][0], 0, 0, 0);
            }
        }
    }

    // ---- epilogue: bias, store raw fp32 NHWC, group stats ----
    float bv[NT], sa[NT], sa2[NT];
#pragma unroll
    for (int nt = 0; nt < NT; nt++) { bv[nt] = bias[nt * 16 + lm]; sa[nt] = 0.f; sa2[nt] = 0.f; }

#pragma unroll
    for (int f = 0; f < 2; f++)
#pragma unroll
        for (int r = 0; r < 4; r++) {
            int x = wid * 16 + f * 64 + lk * 4 + r;
            size_t pxo = ((size_t)b * HW + y * W + x) * COUT;
#pragma unroll
            for (int nt = 0; nt < NT; nt++) {
                float v = acc[f][nt][r] + bv[nt];
                outraw[pxo + nt * 16 + lm] = v;
                sa[nt] += v;
                sa2[nt] += v * v;
            }
        }

    constexpr int CgO = COUT / Gout;
#pragma unroll
    for (int nt = 0; nt < NT; nt++) {
        float s = sa[nt], s2 = sa2[nt];
        s += __shfl_xor(s, 16); s2 += __shfl_xor(s2, 16);
        s += __shfl_xor(s, 32); s2 += __shfl_xor(s2, 32);
#pragma unroll
        for (int m = 1; m < CgO; m <<= 1) { s += __shfl_xor(s, m); s2 += __shfl_xor(s2, m); }
        if (l < 16 && (lm & (CgO - 1)) == 0) {
            int g = (nt * 16 + lm) / CgO;
            atomicAdd(&stats_out[((size_t)b * Gout + g) * 2], s);
            atomicAdd(&stats_out[((size_t)b * Gout + g) * 2 + 1], s2);
        }
    }
}

// ================= psik: GN+SiLU on fp32 NHWC h3/p2 + 1x1 convs -> k, psi =================
__global__ void psik_k(const float* __restrict__ h3, const float* __restrict__ p2,
                       const float* __restrict__ kg3, const float* __restrict__ kbeta3,
                       const float* __restrict__ st3,
                       const float* __restrict__ pg2, const float* __restrict__ pbeta2,
                       const float* __restrict__ stp2,
                       const float* __restrict__ kw4, const float* __restrict__ kb4,
                       const float* __restrict__ pw3, const float* __restrict__ pb3,
                       float* __restrict__ outk, float* __restrict__ outpsi, int Bc) {
    int n = blockIdx.x * 256 + threadIdx.x;
    if (n >= Bc * HW) return;
    int b = n >> 14;
    int rem = n & (HW - 1);
    int i = rem >> 7;
    int j = rem & 127;

    constexpr float inv = 1.f / (float)(4 * HW);
    float a3[4], c3[4], ap[4], cp[4];
#pragma unroll
    for (int g = 0; g < 4; g++) {
        float s = st3[((size_t)b * 4 + g) * 2];
        float s2 = st3[((size_t)b * 4 + g) * 2 + 1];
        float m = s * inv;
        a3[g] = rsqrtf(s2 * inv - m * m + 1e-5f);
        c3[g] = m;
        s = stp2[((size_t)b * 4 + g) * 2];
        s2 = stp2[((size_t)b * 4 + g) * 2 + 1];
        m = s * inv;
        ap[g] = rsqrtf(s2 * inv - m * m + 1e-5f);
        cp[g] = m;
    }

    float hv[16], pv[16];
    const float4* hp = (const float4*)(h3 + ((size_t)b * HW + rem) * 16);
    const float4* pp = (const float4*)(p2 + ((size_t)b * HW + rem) * 16);
#pragma unroll
    for (int t = 0; t < 4; t++) {
        float4 u = hp[t];
        hv[4 * t] = u.x; hv[4 * t + 1] = u.y; hv[4 * t + 2] = u.z; hv[4 * t + 3] = u.w;
        float4 w = pp[t];
        pv[4 * t] = w.x; pv[4 * t + 1] = w.y; pv[4 * t + 2] = w.z; pv[4 * t + 3] = w.w;
    }

    float dk = kb4[0], dp = pb3[0];
#pragma unroll
    for (int c = 0; c < 16; c++) {
        int g = c >> 2;
        float a = kg3[c] * a3[g];
        float t = fmaf(hv[c] - c3[g], a, kbeta3[c]);
        dk = fmaf(kw4[c], silu_f(t), dk);
        a = pg2[c] * ap[g];
        t = fmaf(pv[c] - cp[g], a, pbeta2[c]);
        dp = fmaf(pw3[c], silu_f(t), dp);
    }
    float k = 0.5f * (1.f + 0.3f * tanhf(dk));
    float psr = 0.05f * tanhf(dp);
    float X = -1.f + 2.f * j / 127.f;
    float Y = -1.f + 2.f * i / 127.f;
    float r = sqrtf(X * X + Y * Y);
    outk[n] = k;
    outpsi[n] = fmaf(k, r, psr);
}

// ================= blur + final =================
static __device__ __constant__ float GW0 = 0.40261994689423467f;
static __device__ __constant__ float GW1 = 0.24420134200323348f;
static __device__ __constant__ float GW2 = 0.05448868454964433f;

__global__ void blur_h_k(const float* __restrict__ in, float* __restrict__ out, int B) {
    int n = blockIdx.x * 256 + threadIdx.x;
    if (n >= B * HW) return;
    int j = n & 127;
    const float* row = in + (n - j);
    int jm2 = j - 2; jm2 = jm2 < 0 ? -jm2 : jm2;
    int jm1 = j - 1; jm1 = jm1 < 0 ? -jm1 : jm1;
    int jp1 = j + 1; jp1 = jp1 > 127 ? 254 - jp1 : jp1;
    int jp2 = j + 2; jp2 = jp2 > 127 ? 254 - jp2 : jp2;
    out[n] = GW2 * (row[jm2] + row[jp2]) + GW1 * (row[jm1] + row[jp1]) + GW0 * row[j];
}

__global__ void blur_v_k(const float* __restrict__ in, float* __restrict__ out, int B) {
    int n = blockIdx.x * 256 + threadIdx.x;
    if (n >= B * HW) return;
    int rem = n & (HW - 1);
    int i = rem >> 7;
    int j = rem & 127;
    const float* pl = in + (n - rem) + j;
    int im2 = i - 2; im2 = im2 < 0 ? -im2 : im2;
    int im1 = i - 1; im1 = im1 < 0 ? -im1 : im1;
    int ip1 = i + 1; ip1 = ip1 > 127 ? 254 - ip1 : ip1;
    int ip2 = i + 2; ip2 = ip2 > 127 ? 254 - ip2 : ip2;
    out[n] = GW2 * (pl[im2 * W] + pl[ip2 * W]) + GW1 * (pl[im1 * W] + pl[ip1 * W]) + GW0 * pl[i * W];
}

__global__ void final_k(const float* __restrict__ psis, const float* __restrict__ img,
                        float* __restrict__ osrc, float* __restrict__ oax,
                        float* __restrict__ oay, int B) {
    int n = blockIdx.x * 256 + threadIdx.x;
    if (n >= B * HW) return;
    int rem = n & (HW - 1);
    int i = rem >> 7;
    int j = rem & 127;
    const float* pl = psis + (n - rem);

    float gx;
    if (j == 0)        gx = pl[i * W + 1] - pl[i * W];
    else if (j == 127) gx = pl[i * W + 127] - pl[i * W + 126];
    else               gx = (pl[i * W + j + 1] - pl[i * W + j - 1]) * 0.5f;
    gx *= 63.5f;

    float gy;
    if (i == 0)        gy = pl[W + j] - pl[j];
    else if (i == 127) gy = pl[127 * W + j] - pl[126 * W + j];
    else               gy = (pl[(i + 1) * W + j] - pl[(i - 1) * W + j]) * 0.5f;
    gy *= 63.5f;

    float ax = 0.5f * tanhf(gx * 2.f);
    float ay = 0.5f * tanhf(gy * 2.f);

    float X = -1.f + 2.f * j / 127.f;
    float Y = -1.f + 2.f * i / 127.f;
    float bx = fminf(fmaxf(X - ax, -1.f), 1.f);
    float by = fminf(fmaxf(Y - ay, -1.f), 1.f);
    float px = (bx + 1.f) * 0.5f * 127.f;
    float py = (by + 1.f) * 0.5f * 127.f;
    float x0f = floorf(px), y0f = floorf(py);
    float wx = px - x0f, wy = py - y0f;
    int x0i = min(max((int)x0f, 0), 127);
    int x1i = min(x0i + 1, 127);
    int y0i = min(max((int)y0f, 0), 127);
    int y1i = min(y0i + 1, 127);

    const float* im = img + (size_t)(n >> 14) * HW;
    float v00 = im[y0i * W + x0i], v01 = im[y0i * W + x1i];
    float v10 = im[y1i * W + x0i], v11 = im[y1i * W + x1i];
    float wrp = v00 * (1.f - wx) * (1.f - wy) + v01 * wx * (1.f - wy) +
                v10 * (1.f - wx) * wy + v11 * wx * wy;

    osrc[n] = 0.9f * wrp + 0.1f * im[rem];
    oax[n] = ax;
    oay[n] = ay;
}

// ================= launch =================
extern "C" void kernel_launch(void* const* d_in, const int* in_sizes, int n_in,
                              void* d_out, int out_size, void* d_ws, size_t ws_size,
                              hipStream_t stream) {
    const float* img = (const float*)d_in[0];
    const int B = in_sizes[0] / HW;  // 64
    const int npix = B * HW;

    char* base = (char*)d_ws;
    size_t off = 0;
    auto alloc = [&](size_t bytes) {
        char* p = base + off;
        off = (off + bytes + 255) & ~(size_t)255;
        return p;
    };

    float* tmp   = (float*)alloc((size_t)npix * 4);
    float* psis  = (float*)alloc((size_t)npix * 4);
    float* polar = (float*)alloc(3 * HW * 4);
    float* wt1   = (float*)alloc(4 * 9 * 32 * 4);
    float* wtp1  = (float*)alloc(4 * 9 * 16 * 4);
    ushort* wpk2h = (ushort*)alloc(9 * 2 * 64 * 8 * 2);
    ushort* wpk2l = (ushort*)alloc(9 * 2 * 64 * 8 * 2);
    ushort* wpk3h = (ushort*)alloc(9 * 64 * 8 * 2);
    ushort* wpk3l = (ushort*)alloc(9 * 64 * 8 * 2);
    ushort* wpkph = (ushort*)alloc(9 * 64 * 8 * 2);
    ushort* wpkpl = (ushort*)alloc(9 * 64 * 8 * 2);
    int nstats = B * 56;
    float* stats = (float*)alloc((size_t)nstats * 4);
    float* st1  = stats;                 // B*8*2
    float* st2  = st1 + (size_t)B * 16;  // B*8*2
    float* st3  = st2 + (size_t)B * 16;  // B*4*2
    float* stp1 = st3 + (size_t)B * 8;   // B*4*2
    float* stp2 = stp1 + (size_t)B * 8;  // B*4*2
    size_t head = off;

    // chunk: two raw fp32 NHWC-32 buffers
    int BC = B;
    while (BC > 1) {
        size_t need = head + 2 * ((size_t)BC * HW * 32 * 4 + 256);
        if (need <= ws_size) break;
        BC >>= 1;
    }
    float* R  = (float*)alloc((size_t)BC * HW * 32 * 4);
    float* R2 = (float*)alloc((size_t)BC * HW * 32 * 4);
    float* h3R = R;                          // [BC][HW][16] (overwrites conv1 raw)
    float* p2R = R + (size_t)BC * HW * 16;   // [BC][HW][16]
    float* RpR = R2;                         // convp1 raw (overwrites conv2 raw)

    float* outsrc = (float*)d_out;
    float* outk   = outsrc + (size_t)npix;
    float* outpsi = outk + (size_t)npix;
    float* outax  = outpsi + (size_t)npix;
    float* outay  = outax + (size_t)npix;

    PrepArgs pa;
    pa.w1 = (const float*)d_in[1]; pa.w2 = (const float*)d_in[5];
    pa.w3 = (const float*)d_in[9]; pa.wp1 = (const float*)d_in[15];
    pa.wp2 = (const float*)d_in[19];
    pa.wt1 = wt1; pa.wtp1 = wtp1; pa.polar = polar; pa.stats = stats;
    pa.wpk2h = wpk2h; pa.wpk2l = wpk2l; pa.wpk3h = wpk3h; pa.wpk3l = wpk3l;
    pa.wpkph = wpkph; pa.wpkpl = wpkpl; pa.nstats = nstats;
    prep_k<<<128, 256, 0, stream>>>(pa);

    for (int b0 = 0; b0 < B; b0 += BC) {
        const float* imgc = img + (size_t)b0 * HW;
        dim3 cg1(H / 2, BC), cgm(H, BC);

        // k-tower
        conv1_k<32, 8><<<cg1, 256, 0, stream>>>(imgc, polar, wt1, (const float*)d_in[2],
                                                R, st1 + (size_t)b0 * 16);
        conv_mfma2<32, 32, 8, 8><<<cgm, 256, 0, stream>>>(
            R, st1 + (size_t)b0 * 16, (const float*)d_in[3], (const float*)d_in[4],
            (const float*)d_in[6], (const short8*)wpk2h, (const short8*)wpk2l,
            R2, st2 + (size_t)b0 * 16);
        conv_mfma2<32, 16, 8, 4><<<cgm, 256, 0, stream>>>(
            R2, st2 + (size_t)b0 * 16, (const float*)d_in[7], (const float*)d_in[8],
            (const float*)d_in[10], (const short8*)wpk3h, (const short8*)wpk3l,
            h3R, st3 + (size_t)b0 * 8);

        // p-tower
        conv1_k<16, 4><<<cg1, 256, 0, stream>>>(imgc, polar, wtp1, (const float*)d_in[16],
                                                RpR, stp1 + (size_t)b0 * 8);
        conv_mfma2<16, 16, 4, 4><<<cgm, 256, 0, stream>>>(
            RpR, stp1 + (size_t)b0 * 8, (const float*)d_in[17], (const float*)d_in[18],
            (const float*)d_in[20], (const short8*)wpkph, (const short8*)wpkpl,
            p2R, stp2 + (size_t)b0 * 8);

        int pgrid = (BC * HW + 255) / 256;
        psik_k<<<pgrid, 256, 0, stream>>>(h3R, p2R,
            (const float*)d_in[11], (const float*)d_in[12], st3 + (size_t)b0 * 8,
            (const float*)d_in[21], (const float*)d_in[22], stp2 + (size_t)b0 * 8,
            (const float*)d_in[13], (const float*)d_in[14],
            (const float*)d_in[23], (const float*)d_in[24],
            outk + (size_t)b0 * HW, outpsi + (size_t)b0 * HW, BC);
    }

    int pgrid = (npix + 255) / 256;
    blur_h_k<<<pgrid, 256, 0, stream>>>(outpsi, tmp, B);
    blur_v_k<<<pgrid, 256, 0, stream>>>(tmp, psis, B);
    final_k<<<pgrid, 256, 0, stream>>>(psis, img, outsrc, outax, outay, B);
}

// Round 7
// 438.428 us; speedup vs baseline: 2.8198x; 2.3307x over previous
//
#include <hip/hip_runtime.h>

static constexpr int H = 128, W = 128, HW = H * W;

typedef __attribute__((ext_vector_type(8))) short short8;
typedef __attribute__((ext_vector_type(4))) float f32x4;
typedef unsigned int uint;
typedef unsigned short ushort;

__device__ __forceinline__ float silu_f(float v) { return v / (1.f + __expf(-v)); }
__device__ __forceinline__ ushort f2bf(float f) {
    uint u = __builtin_bit_cast(uint, f);
    return (ushort)((u + 0x7FFFu + ((u >> 16) & 1u)) >> 16);
}
__device__ __forceinline__ float bf2f(ushort s) {
    return __builtin_bit_cast(float, (uint)s << 16);
}

// ================= prep: stats zero, polar, wt transposes, split MFMA weight packs =================
struct PrepArgs {
    const float *w1, *w2, *w3, *wp1, *wp2;
    float *wt1, *wtp1, *polar, *stats;
    ushort *wpk2h, *wpk2l, *wpk3h, *wpk3l, *wpkph, *wpkpl;
    int nstats;
};

__global__ void prep_k(PrepArgs a) {
    int tid = blockIdx.x * 256 + threadIdx.x;
    int stride = gridDim.x * 256;
    for (int i = tid; i < a.nstats; i += stride) a.stats[i] = 0.f;
    for (int i = tid; i < HW; i += stride) {
        int yy = i >> 7, xx = i & 127;
        float X = -1.f + 2.f * xx / 127.f;
        float Y = -1.f + 2.f * yy / 127.f;
        float r = sqrtf(X * X + Y * Y);
        float inv = (r > 0.f) ? 1.f / r : 0.f;
        a.polar[i] = r;
        a.polar[HW + i] = (r > 0.f) ? X * inv : 1.f;
        a.polar[2 * HW + i] = Y * inv;
    }
    for (int i = tid; i < 4 * 9 * 32; i += stride) {
        int cout = i / 36, rem = i % 36;
        a.wt1[rem * 32 + cout] = a.w1[i];
    }
    for (int i = tid; i < 4 * 9 * 16; i += stride) {
        int cout = i / 36, rem = i % 36;
        a.wtp1[rem * 16 + cout] = a.wp1[i];
    }
    // wpack2: conv2 (32->32), [(q*2+nt)][lane][8], k=(l>>4)*8+j=cin, n=nt*16+(l&15)
    for (int i = tid; i < 9 * 2 * 64 * 8; i += stride) {
        int j = i & 7, l = (i >> 3) & 63, t = i >> 9;
        int q = t >> 1, nt = t & 1;
        int k = (l >> 4) * 8 + j;
        int n = nt * 16 + (l & 15);
        int ky = q / 3, kx = q % 3;
        float w = a.w2[((n * 32 + k) * 3 + ky) * 3 + kx];
        ushort h = f2bf(w);
        a.wpk2h[i] = h;
        a.wpk2l[i] = f2bf(w - bf2f(h));
    }
    // wpack3: conv3 (32->16), [q][lane][8]
    for (int i = tid; i < 9 * 64 * 8; i += stride) {
        int j = i & 7, l = (i >> 3) & 63, q = i >> 9;
        int k = (l >> 4) * 8 + j;
        int n = l & 15;
        int ky = q / 3, kx = q % 3;
        float w = a.w3[((n * 32 + k) * 3 + ky) * 3 + kx];
        ushort h = f2bf(w);
        a.wpk3h[i] = h;
        a.wpk3l[i] = f2bf(w - bf2f(h));
    }
    // wpackp: convp2 (16->16), B1=[Whi|Whi], B2=[Wlo|Wlo] over k=32
    for (int i = tid; i < 9 * 64 * 8; i += stride) {
        int j = i & 7, l = (i >> 3) & 63, q = i >> 9;
        int k = (l >> 4) * 8 + j;
        int cin = k & 15;
        int n = l & 15;
        float w = a.wp2[((n * 16 + cin) * 3 + q / 3) * 3 + q % 3];
        ushort h = f2bf(w);
        a.wpkph[i] = h;
        a.wpkpl[i] = f2bf(w - bf2f(h));
    }
}

// ================= conv1 / convp1: fp32 direct (K=36), out = raw fp32 NHWC + stats =================
template <int COUT, int G>
__global__ __launch_bounds__(256) void conv1_k(
    const float* __restrict__ img, const float* __restrict__ polar,
    const float* __restrict__ wt, const float* __restrict__ bias,
    float* __restrict__ outraw, float* __restrict__ stats) {
    const int tid = threadIdx.x;
    const int y = blockIdx.x * 2 + (tid >> 7);
    const int x = tid & 127;
    const int b = blockIdx.y;

    float acc[COUT];
#pragma unroll
    for (int c = 0; c < COUT; c++) acc[c] = bias[c];

#pragma unroll
    for (int cin = 0; cin < 4; cin++) {
        const float* pl = (cin == 0) ? img + (size_t)b * HW : polar + (size_t)(cin - 1) * HW;
#pragma unroll
        for (int ky = 0; ky < 3; ky++) {
            int yy = y + ky - 1;
            if (yy >= 0 && yy < H) {
                const float* row = pl + yy * W;
                float v1 = row[x];
                float v0 = (x > 0) ? row[x - 1] : 0.f;
                float v2 = (x < 127) ? row[x + 1] : 0.f;
                const float* wr = wt + (cin * 9 + ky * 3) * COUT;
#pragma unroll
                for (int c = 0; c < COUT; c++) {
                    acc[c] = fmaf(wr[c], v0, acc[c]);
                    acc[c] = fmaf(wr[COUT + c], v1, acc[c]);
                    acc[c] = fmaf(wr[2 * COUT + c], v2, acc[c]);
                }
            }
        }
    }

    float4* ob = (float4*)(outraw + ((size_t)b * HW + y * W + x) * COUT);
#pragma unroll
    for (int i = 0; i < COUT / 4; i++)
        ob[i] = make_float4(acc[4 * i], acc[4 * i + 1], acc[4 * i + 2], acc[4 * i + 3]);

    constexpr int CgO = COUT / G;
    __shared__ float sred[4][G][2];
    const int lane = tid & 63, wid = tid >> 6;
#pragma unroll
    for (int g = 0; g < G; g++) {
        float s = 0.f, s2 = 0.f;
#pragma unroll
        for (int c = g * CgO; c < (g + 1) * CgO; c++) { s += acc[c]; s2 += acc[c] * acc[c]; }
#pragma unroll
        for (int off = 32; off > 0; off >>= 1) {
            s += __shfl_down(s, off);
            s2 += __shfl_down(s2, off);
        }
        if (lane == 0) { sred[wid][g][0] = s; sred[wid][g][1] = s2; }
    }
    __syncthreads();
    if (tid < G) {
        float s = 0.f, s2 = 0.f;
#pragma unroll
        for (int w = 0; w < 4; w++) { s += sred[w][tid][0]; s2 += sred[w][tid][1]; }
        atomicAdd(&stats[((size_t)b * G + tid) * 2], s);
        atomicAdd(&stats[((size_t)b * G + tid) * 2 + 1], s2);
    }
}

// ======== rolling-row fused MFMA conv 3x3 ========
// Block: 256 thr, computes ROWS=8 output rows x 128 px. 3-slot LDS ring, XOR-swizzled.
// Per row: issue next-row global loads -> MFMA current row -> bar -> silu/split/LDS write -> bar.
// Weights preloaded in VGPRs (wave-split cout for COUT=32).
template <int CIN, int COUT, int Gin, int Gout>
__global__ __launch_bounds__(256, 3) void conv_roll_k(
    const float* __restrict__ raw_in, const float* __restrict__ stats_in,
    const float* __restrict__ gamma, const float* __restrict__ beta,
    const float* __restrict__ bias,
    const short8* __restrict__ wph, const short8* __restrict__ wpl,
    float* __restrict__ outraw, float* __restrict__ stats_out) {

    constexpr int LDSC = 2 * CIN;           // ushorts per px (hi+lo)
    constexpr int SWZM = LDSC / 8 - 1;      // 7 (CIN32), 3 (CIN16)
    constexpr int NCH8 = CIN / 8;
    constexpr int WN = (COUT == 32) ? 2 : 1;
    constexpr int F = (WN == 2) ? 4 : 2;    // 16-px m-tiles per wave
    constexpr int ROWS = 8;
    constexpr int ROWB = 128 * LDSC * 2;    // bytes per ring slot
    constexpr int CHUNKS = 128 * NCH8 / 256;

    __shared__ __align__(16) ushort ring[3 * 128 * LDSC];
    __shared__ float la[CIN], lc[CIN];

    const int tid = threadIdx.x;
    const int wid = tid >> 6, l = tid & 63;
    const int lm = l & 15, lk = l >> 4;
    const int y0 = blockIdx.x * ROWS;
    const int b = blockIdx.y;
    const int wn = (WN == 2) ? (wid & 1) : 0;
    const int pxb = (WN == 2) ? ((wid >> 1) * 64) : (wid * 32);
    const int ch = wn * 16 + lm;

    if (tid < CIN) {
        constexpr float inv = 1.f / ((CIN / Gin) * (float)HW);
        int g = tid / (CIN / Gin);
        float s = stats_in[((size_t)b * Gin + g) * 2];
        float s2 = stats_in[((size_t)b * Gin + g) * 2 + 1];
        float m = s * inv;
        float rs = rsqrtf(s2 * inv - m * m + 1e-5f);
        float aa = gamma[tid] * rs;
        la[tid] = aa;
        lc[tid] = beta[tid] - m * aa;
    }
    __syncthreads();

    short8 wh[9], wl[9];
#pragma unroll
    for (int q = 0; q < 9; q++) {
        wh[q] = wph[(q * WN + wn) * 64 + l];
        wl[q] = wpl[(q * WN + wn) * 64 + l];
    }
    const float bv = bias[ch];
    const short8 Z8 = {0, 0, 0, 0, 0, 0, 0, 0};
    char* tbw = (char*)ring;

    auto load_row = [&](int ys, float4* g0, float4* g1) {
#pragma unroll
        for (int ck = 0; ck < CHUNKS; ck++) {
            int c = tid + ck * 256;
            int px = c / NCH8, ch8 = c % NCH8;
            const float4* gp = (const float4*)(raw_in + (((size_t)b * HW + ys * W + px) * CIN + ch8 * 8));
            g0[ck] = gp[0];
            g1[ck] = gp[1];
        }
    };
    auto stage_row = [&](int ys, int slot, const float4* g0, const float4* g1) {
#pragma unroll
        for (int ck = 0; ck < CHUNKS; ck++) {
            int c = tid + ck * 256;
            int px = c / NCH8, ch8 = c % NCH8;
            short8 hi8, lo8;
            if (ys >= 0 && ys < H) {
                float vv[8] = {g0[ck].x, g0[ck].y, g0[ck].z, g0[ck].w,
                               g1[ck].x, g1[ck].y, g1[ck].z, g1[ck].w};
#pragma unroll
                for (int e = 0; e < 8; e++) {
                    int cc = ch8 * 8 + e;
                    float f = silu_f(fmaf(vv[e], la[cc], lc[cc]));
                    ushort hb = f2bf(f);
                    hi8[e] = (short)hb;
                    lo8[e] = (short)f2bf(f - bf2f(hb));
                }
            } else {
#pragma unroll
                for (int e = 0; e < 8; e++) { hi8[e] = 0; lo8[e] = 0; }
            }
            int inner = px * LDSC * 2 + ch8 * 16;
            int swz = (px & SWZM) << 4;
            char* sb = tbw + slot * ROWB;
            *(short8*)(sb + (inner ^ swz)) = hi8;
            *(short8*)(sb + ((inner + CIN * 2) ^ swz)) = lo8;
        }
    };

    // prologue: rows y0-1, y0, y0+1
    {
        float4 p0[CHUNKS], p1[CHUNKS];
        for (int pr = 0; pr < 3; pr++) {
            int ys = y0 - 1 + pr;
            if (ys >= 0 && ys < H) load_row(ys, p0, p1);
            stage_row(ys, (ys + 3) % 3, p0, p1);
        }
    }
    __syncthreads();

    float sa = 0.f, sa2 = 0.f;
    float4 g0[CHUNKS], g1[CHUNKS];

    for (int r = 0; r < ROWS; r++) {
        const int y = y0 + r;
        const int ys = y + 2;
        const bool do_stage = (r < ROWS - 1);
        if (do_stage && ys < H) load_row(ys, g0, g1);  // issue early, consumed after bar

        f32x4 acc[F];
#pragma unroll
        for (int f = 0; f < F; f++) acc[f] = (f32x4){0.f, 0.f, 0.f, 0.f};

        const char* sbase[3] = {tbw + ((y + 2) % 3) * ROWB,
                                tbw + ((y + 3) % 3) * ROWB,
                                tbw + ((y + 4) % 3) * ROWB};
#pragma unroll
        for (int q = 0; q < 9; q++) {
            const int ky = q / 3, kx = q % 3;
            const char* sb = sbase[ky];
#pragma unroll
            for (int f = 0; f < F; f++) {
                int xb = pxb + f * 16 + lm + kx - 1;
                bool valid = (xb >= 0) && (xb < 128);
                int xbc = min(max(xb, 0), 127);
                int inner = xbc * LDSC * 2;
                int swz = (xbc & SWZM) << 4;
                if constexpr (CIN == 32) {
                    short8 ah = *(const short8*)(sb + ((inner + lk * 16) ^ swz));
                    short8 al = *(const short8*)(sb + ((inner + (lk + 4) * 16) ^ swz));
                    if (!valid) { ah = Z8; al = Z8; }
                    acc[f] = __builtin_amdgcn_mfma_f32_16x16x32_bf16(ah, wh[q], acc[f], 0, 0, 0);
                    acc[f] = __builtin_amdgcn_mfma_f32_16x16x32_bf16(al, wh[q], acc[f], 0, 0, 0);
                    acc[f] = __builtin_amdgcn_mfma_f32_16x16x32_bf16(ah, wl[q], acc[f], 0, 0, 0);
                } else {
                    short8 a = *(const short8*)(sb + ((inner + lk * 16) ^ swz));
                    if (!valid) a = Z8;
                    acc[f] = __builtin_amdgcn_mfma_f32_16x16x32_bf16(a, wh[q], acc[f], 0, 0, 0);
                    acc[f] = __builtin_amdgcn_mfma_f32_16x16x32_bf16(a, wl[q], acc[f], 0, 0, 0);
                }
            }
        }

        // store row + stats accumulate
#pragma unroll
        for (int f = 0; f < F; f++) {
#pragma unroll
            for (int rr = 0; rr < 4; rr++) {
                int x = pxb + f * 16 + lk * 4 + rr;
                float v = acc[f][rr] + bv;
                outraw[((size_t)b * HW + y * W + x) * COUT + ch] = v;
                sa += v;
                sa2 += v * v;
            }
        }
        __syncthreads();
        if (do_stage) stage_row(ys, (ys + 3) % 3, g0, g1);
        __syncthreads();
    }

    // stats: reduce over lk (xor16/32) then over channels within group, then atomics
    float s = sa, s2 = sa2;
    s += __shfl_xor(s, 16); s2 += __shfl_xor(s2, 16);
    s += __shfl_xor(s, 32); s2 += __shfl_xor(s2, 32);
    constexpr int CgO = COUT / Gout;
#pragma unroll
    for (int m = 1; m < CgO; m <<= 1) { s += __shfl_xor(s, m); s2 += __shfl_xor(s2, m); }
    if (l < 16 && (lm & (CgO - 1)) == 0) {
        int g = ch / CgO;
        atomicAdd(&stats_out[((size_t)b * Gout + g) * 2], s);
        atomicAdd(&stats_out[((size_t)b * Gout + g) * 2 + 1], s2);
    }
}

// ================= psik: GN+SiLU on fp32 NHWC h3/p2 + 1x1 convs -> k, psi =================
__global__ void psik_k(const float* __restrict__ h3, const float* __restrict__ p2,
                       const float* __restrict__ kg3, const float* __restrict__ kbeta3,
                       const float* __restrict__ st3,
                       const float* __restrict__ pg2, const float* __restrict__ pbeta2,
                       const float* __restrict__ stp2,
                       const float* __restrict__ kw4, const float* __restrict__ kb4,
                       const float* __restrict__ pw3, const float* __restrict__ pb3,
                       float* __restrict__ outk, float* __restrict__ outpsi, int Bc) {
    int n = blockIdx.x * 256 + threadIdx.x;
    if (n >= Bc * HW) return;
    int b = n >> 14;
    int rem = n & (HW - 1);
    int i = rem >> 7;
    int j = rem & 127;

    constexpr float inv = 1.f / (float)(4 * HW);
    float a3[4], c3[4], ap[4], cp[4];
#pragma unroll
    for (int g = 0; g < 4; g++) {
        float s = st3[((size_t)b * 4 + g) * 2];
        float s2 = st3[((size_t)b * 4 + g) * 2 + 1];
        float m = s * inv;
        a3[g] = rsqrtf(s2 * inv - m * m + 1e-5f);
        c3[g] = m;
        s = stp2[((size_t)b * 4 + g) * 2];
        s2 = stp2[((size_t)b * 4 + g) * 2 + 1];
        m = s * inv;
        ap[g] = rsqrtf(s2 * inv - m * m + 1e-5f);
        cp[g] = m;
    }

    float hv[16], pv[16];
    const float4* hp = (const float4*)(h3 + ((size_t)b * HW + rem) * 16);
    const float4* pp = (const float4*)(p2 + ((size_t)b * HW + rem) * 16);
#pragma unroll
    for (int t = 0; t < 4; t++) {
        float4 u = hp[t];
        hv[4 * t] = u.x; hv[4 * t + 1] = u.y; hv[4 * t + 2] = u.z; hv[4 * t + 3] = u.w;
        float4 w = pp[t];
        pv[4 * t] = w.x; pv[4 * t + 1] = w.y; pv[4 * t + 2] = w.z; pv[4 * t + 3] = w.w;
    }

    float dk = kb4[0], dp = pb3[0];
#pragma unroll
    for (int c = 0; c < 16; c++) {
        int g = c >> 2;
        float a = kg3[c] * a3[g];
        float t = fmaf(hv[c] - c3[g], a, kbeta3[c]);
        dk = fmaf(kw4[c], silu_f(t), dk);
        a = pg2[c] * ap[g];
        t = fmaf(pv[c] - cp[g], a, pbeta2[c]);
        dp = fmaf(pw3[c], silu_f(t), dp);
    }
    float k = 0.5f * (1.f + 0.3f * tanhf(dk));
    float psr = 0.05f * tanhf(dp);
    float X = -1.f + 2.f * j / 127.f;
    float Y = -1.f + 2.f * i / 127.f;
    float r = sqrtf(X * X + Y * Y);
    outk[n] = k;
    outpsi[n] = fmaf(k, r, psr);
}

// ================= blur + final =================
static __device__ __constant__ float GW0 = 0.40261994689423467f;
static __device__ __constant__ float GW1 = 0.24420134200323348f;
static __device__ __constant__ float GW2 = 0.05448868454964433f;

__global__ void blur_h_k(const float* __restrict__ in, float* __restrict__ out, int B) {
    int n = blockIdx.x * 256 + threadIdx.x;
    if (n >= B * HW) return;
    int j = n & 127;
    const float* row = in + (n - j);
    int jm2 = j - 2; jm2 = jm2 < 0 ? -jm2 : jm2;
    int jm1 = j - 1; jm1 = jm1 < 0 ? -jm1 : jm1;
    int jp1 = j + 1; jp1 = jp1 > 127 ? 254 - jp1 : jp1;
    int jp2 = j + 2; jp2 = jp2 > 127 ? 254 - jp2 : jp2;
    out[n] = GW2 * (row[jm2] + row[jp2]) + GW1 * (row[jm1] + row[jp1]) + GW0 * row[j];
}

__global__ void blur_v_k(const float* __restrict__ in, float* __restrict__ out, int B) {
    int n = blockIdx.x * 256 + threadIdx.x;
    if (n >= B * HW) return;
    int rem = n & (HW - 1);
    int i = rem >> 7;
    int j = rem & 127;
    const float* pl = in + (n - rem) + j;
    int im2 = i - 2; im2 = im2 < 0 ? -im2 : im2;
    int im1 = i - 1; im1 = im1 < 0 ? -im1 : im1;
    int ip1 = i + 1; ip1 = ip1 > 127 ? 254 - ip1 : ip1;
    int ip2 = i + 2; ip2 = ip2 > 127 ? 254 - ip2 : ip2;
    out[n] = GW2 * (pl[im2 * W] + pl[ip2 * W]) + GW1 * (pl[im1 * W] + pl[ip1 * W]) + GW0 * pl[i * W];
}

__global__ void final_k(const float* __restrict__ psis, const float* __restrict__ img,
                        float* __restrict__ osrc, float* __restrict__ oax,
                        float* __restrict__ oay, int B) {
    int n = blockIdx.x * 256 + threadIdx.x;
    if (n >= B * HW) return;
    int rem = n & (HW - 1);
    int i = rem >> 7;
    int j = rem & 127;
    const float* pl = psis + (n - rem);

    float gx;
    if (j == 0)        gx = pl[i * W + 1] - pl[i * W];
    else if (j == 127) gx = pl[i * W + 127] - pl[i * W + 126];
    else               gx = (pl[i * W + j + 1] - pl[i * W + j - 1]) * 0.5f;
    gx *= 63.5f;

    float gy;
    if (i == 0)        gy = pl[W + j] - pl[j];
    else if (i == 127) gy = pl[127 * W + j] - pl[126 * W + j];
    else               gy = (pl[(i + 1) * W + j] - pl[(i - 1) * W + j]) * 0.5f;
    gy *= 63.5f;

    float ax = 0.5f * tanhf(gx * 2.f);
    float ay = 0.5f * tanhf(gy * 2.f);

    float X = -1.f + 2.f * j / 127.f;
    float Y = -1.f + 2.f * i / 127.f;
    float bx = fminf(fmaxf(X - ax, -1.f), 1.f);
    float by = fminf(fmaxf(Y - ay, -1.f), 1.f);
    float px = (bx + 1.f) * 0.5f * 127.f;
    float py = (by + 1.f) * 0.5f * 127.f;
    float x0f = floorf(px), y0f = floorf(py);
    float wx = px - x0f, wy = py - y0f;
    int x0i = min(max((int)x0f, 0), 127);
    int x1i = min(x0i + 1, 127);
    int y0i = min(max((int)y0f, 0), 127);
    int y1i = min(y0i + 1, 127);

    const float* im = img + (size_t)(n >> 14) * HW;
    float v00 = im[y0i * W + x0i], v01 = im[y0i * W + x1i];
    float v10 = im[y1i * W + x0i], v11 = im[y1i * W + x1i];
    float wrp = v00 * (1.f - wx) * (1.f - wy) + v01 * wx * (1.f - wy) +
                v10 * (1.f - wx) * wy + v11 * wx * wy;

    osrc[n] = 0.9f * wrp + 0.1f * im[rem];
    oax[n] = ax;
    oay[n] = ay;
}

// ================= launch =================
extern "C" void kernel_launch(void* const* d_in, const int* in_sizes, int n_in,
                              void* d_out, int out_size, void* d_ws, size_t ws_size,
                              hipStream_t stream) {
    const float* img = (const float*)d_in[0];
    const int B = in_sizes[0] / HW;  // 64
    const int npix = B * HW;

    char* base = (char*)d_ws;
    size_t off = 0;
    auto alloc = [&](size_t bytes) {
        char* p = base + off;
        off = (off + bytes + 255) & ~(size_t)255;
        return p;
    };

    float* tmp   = (float*)alloc((size_t)npix * 4);
    float* psis  = (float*)alloc((size_t)npix * 4);
    float* polar = (float*)alloc(3 * HW * 4);
    float* wt1   = (float*)alloc(4 * 9 * 32 * 4);
    float* wtp1  = (float*)alloc(4 * 9 * 16 * 4);
    ushort* wpk2h = (ushort*)alloc(9 * 2 * 64 * 8 * 2);
    ushort* wpk2l = (ushort*)alloc(9 * 2 * 64 * 8 * 2);
    ushort* wpk3h = (ushort*)alloc(9 * 64 * 8 * 2);
    ushort* wpk3l = (ushort*)alloc(9 * 64 * 8 * 2);
    ushort* wpkph = (ushort*)alloc(9 * 64 * 8 * 2);
    ushort* wpkpl = (ushort*)alloc(9 * 64 * 8 * 2);
    int nstats = B * 56;
    float* stats = (float*)alloc((size_t)nstats * 4);
    float* st1  = stats;                 // B*8*2
    float* st2  = st1 + (size_t)B * 16;  // B*8*2
    float* st3  = st2 + (size_t)B * 16;  // B*4*2
    float* stp1 = st3 + (size_t)B * 8;   // B*4*2
    float* stp2 = stp1 + (size_t)B * 8;  // B*4*2
    size_t head = off;

    int BC = B;
    while (BC > 1) {
        size_t need = head + 2 * ((size_t)BC * HW * 32 * 4 + 256);
        if (need <= ws_size) break;
        BC >>= 1;
    }
    float* R  = (float*)alloc((size_t)BC * HW * 32 * 4);
    float* R2 = (float*)alloc((size_t)BC * HW * 32 * 4);
    float* h3R = R;                          // [BC][HW][16]
    float* p2R = R + (size_t)BC * HW * 16;   // [BC][HW][16]
    float* RpR = R2;                         // convp1 raw

    float* outsrc = (float*)d_out;
    float* outk   = outsrc + (size_t)npix;
    float* outpsi = outk + (size_t)npix;
    float* outax  = outpsi + (size_t)npix;
    float* outay  = outax + (size_t)npix;

    PrepArgs pa;
    pa.w1 = (const float*)d_in[1]; pa.w2 = (const float*)d_in[5];
    pa.w3 = (const float*)d_in[9]; pa.wp1 = (const float*)d_in[15];
    pa.wp2 = (const float*)d_in[19];
    pa.wt1 = wt1; pa.wtp1 = wtp1; pa.polar = polar; pa.stats = stats;
    pa.wpk2h = wpk2h; pa.wpk2l = wpk2l; pa.wpk3h = wpk3h; pa.wpk3l = wpk3l;
    pa.wpkph = wpkph; pa.wpkpl = wpkpl; pa.nstats = nstats;
    prep_k<<<128, 256, 0, stream>>>(pa);

    for (int b0 = 0; b0 < B; b0 += BC) {
        const float* imgc = img + (size_t)b0 * HW;
        dim3 cg1(H / 2, BC), cgr(H / 8, BC);

        // k-tower
        conv1_k<32, 8><<<cg1, 256, 0, stream>>>(imgc, polar, wt1, (const float*)d_in[2],
                                                R, st1 + (size_t)b0 * 16);
        conv_roll_k<32, 32, 8, 8><<<cgr, 256, 0, stream>>>(
            R, st1 + (size_t)b0 * 16, (const float*)d_in[3], (const float*)d_in[4],
            (const float*)d_in[6], (const short8*)wpk2h, (const short8*)wpk2l,
            R2, st2 + (size_t)b0 * 16);
        conv_roll_k<32, 16, 8, 4><<<cgr, 256, 0, stream>>>(
            R2, st2 + (size_t)b0 * 16, (const float*)d_in[7], (const float*)d_in[8],
            (const float*)d_in[10], (const short8*)wpk3h, (const short8*)wpk3l,
            h3R, st3 + (size_t)b0 * 8);

        // p-tower
        conv1_k<16, 4><<<cg1, 256, 0, stream>>>(imgc, polar, wtp1, (const float*)d_in[16],
                                                RpR, stp1 + (size_t)b0 * 8);
        conv_roll_k<16, 16, 4, 4><<<cgr, 256, 0, stream>>>(
            RpR, stp1 + (size_t)b0 * 8, (const float*)d_in[17], (const float*)d_in[18],
            (const float*)d_in[20], (const short8*)wpkph, (const short8*)wpkpl,
            p2R, stp2 + (size_t)b0 * 8);

        int pgrid = (BC * HW + 255) / 256;
        psik_k<<<pgrid, 256, 0, stream>>>(h3R, p2R,
            (const float*)d_in[11], (const float*)d_in[12], st3 + (size_t)b0 * 8,
            (const float*)d_in[21], (const float*)d_in[22], stp2 + (size_t)b0 * 8,
            (const float*)d_in[13], (const float*)d_in[14],
            (const float*)d_in[23], (const float*)d_in[24],
            outk + (size_t)b0 * HW, outpsi + (size_t)b0 * HW, BC);
    }

    int pgrid = (npix + 255) / 256;
    blur_h_k<<<pgrid, 256, 0, stream>>>(outpsi, tmp, B);
    blur_v_k<<<pgrid, 256, 0, stream>>>(tmp, psis, B);
    final_k<<<pgrid, 256, 0, stream>>>(psis, img, outsrc, outax, outay, B);
}